// Round 4
// baseline (268.917 us; speedup 1.0000x reference)
//
#include <hip/hip_runtime.h>

// H2GCN: CSR build -> bf16 SpMM x2 (unroll-8) -> fused MFMA GEMM.
// Round-4 structure: W fragments read DIRECTLY from global (L2-resident) in
// both stage B and stage C -> no W staging, no per-kk barriers; LDS holds only
// the 64x256 in-tile (reused for t), XOR-swizzled, staged via global_load_lds.

#define FD 256   // D == H == 256
#define CO 64    // out channels
#define SB 512   // scan block

using frag_ab = __attribute__((ext_vector_type(8))) short;  // 8 bf16
using f32x4   = __attribute__((ext_vector_type(4))) float;
typedef unsigned short u16;
typedef unsigned int   u32;

__device__ __forceinline__ u16 f2bf(float f) {
    u32 u = __builtin_bit_cast(u32, f);
    return (u16)((u + 0x7FFFu + ((u >> 16) & 1u)) >> 16);
}
__device__ __forceinline__ float bf2f(u16 u) {
    u32 v = ((u32)u) << 16;
    return __builtin_bit_cast(float, v);
}

__device__ __forceinline__ void gll16(const void* g, void* l) {
    __builtin_amdgcn_global_load_lds(
        (const __attribute__((address_space(1))) u32*)g,
        (__attribute__((address_space(3))) u32*)l, 16, 0, 0);
}

#define BAR()  __builtin_amdgcn_s_barrier()
#define WLG0() asm volatile("s_waitcnt lgkmcnt(0)" ::: "memory")
#define WVM0() asm volatile("s_waitcnt vmcnt(0)" ::: "memory")

// ---------------- CSR build ----------------
__global__ void init_kernel(int* deg, int* fill, int n) {
    int i = blockIdx.x * blockDim.x + threadIdx.x;
    if (i < n) { deg[i] = 1; fill[i] = 0; }
}
__global__ void count_kernel(const int* __restrict__ ei0, int* deg, int e) {
    int i = blockIdx.x * blockDim.x + threadIdx.x;
    if (i < e) atomicAdd(&deg[ei0[i]], 1);
}
__global__ void scan1(const int* __restrict__ deg, int* __restrict__ rowptr,
                      int* __restrict__ bsum, float* __restrict__ dis, int n) {
    __shared__ int sh[SB];
    int tid = threadIdx.x;
    int i = blockIdx.x * SB + tid;
    int v = (i < n) ? deg[i] : 0;
    if (i < n) dis[i] = rsqrtf((float)v);
    sh[tid] = v;
    __syncthreads();
    for (int off = 1; off < SB; off <<= 1) {
        int add = (tid >= off) ? sh[tid - off] : 0;
        __syncthreads();
        sh[tid] += add;
        __syncthreads();
    }
    if (i < n) rowptr[i] = sh[tid] - v;
    if (tid == SB - 1) bsum[blockIdx.x] = sh[tid];
}
__global__ void scan2(const int* __restrict__ bsum, int* __restrict__ bscan, int nb) {
    __shared__ int sh[128];
    int tid = threadIdx.x;
    int v = (tid < nb) ? bsum[tid] : 0;
    sh[tid] = v;
    __syncthreads();
    for (int off = 1; off < 128; off <<= 1) {
        int add = (tid >= off) ? sh[tid - off] : 0;
        __syncthreads();
        sh[tid] += add;
        __syncthreads();
    }
    if (tid < nb) bscan[tid] = sh[tid] - v;
    if (tid == nb - 1) bscan[nb] = sh[tid];
}
__global__ void scan3(int* rowptr, const int* __restrict__ bscan, int n, int nb) {
    int i = blockIdx.x * 256 + threadIdx.x;
    if (i < n) rowptr[i] += bscan[i / SB];
    if (i == n) rowptr[n] = bscan[nb];
}
__global__ void fill_kernel(const int* __restrict__ ei, const float* __restrict__ dis,
                            const int* __restrict__ rowptr, int* fill,
                            int* __restrict__ col, float* __restrict__ wv, int e, int n) {
    int i = blockIdx.x * blockDim.x + threadIdx.x;
    if (i >= e + n) return;
    int r, c;
    if (i < e) { r = ei[i]; c = ei[e + i]; }
    else       { r = i - e; c = r; }
    float w = dis[r] * dis[c];
    int pos = rowptr[r] + atomicAdd(&fill[r], 1);
    col[pos] = c;
    wv[pos]  = w;
}

// ---------------- dtype prep ----------------
__global__ void conv_kernel(const float* __restrict__ x, u16* __restrict__ xb, int total4) {
    int i = blockIdx.x * blockDim.x + threadIdx.x;
    if (i < total4) {
        float4 v = ((const float4*)x)[i];
        ushort4 o;
        o.x = f2bf(v.x); o.y = f2bf(v.y); o.z = f2bf(v.z); o.w = f2bf(v.w);
        ((ushort4*)xb)[i] = o;
    }
}
__global__ void wtrans_kernel(const float* __restrict__ W0, const float* __restrict__ W1,
                              const float* __restrict__ W2, const float* __restrict__ Wc,
                              u16* __restrict__ WkT, u16* __restrict__ WcT) {
    __shared__ u16 tl[64][65];
    int b = blockIdx.x;
    const float* src; u16* dst; int R, C, r0, c0;
    if (b < 48) {
        int k = b >> 4, t = b & 15;
        src = (k == 0) ? W0 : (k == 1) ? W1 : W2;
        dst = WkT + k * 65536;
        R = 256; C = 256; r0 = (t >> 2) * 64; c0 = (t & 3) * 64;
    } else {
        int t = b - 48;
        src = Wc; dst = WcT;
        R = 768; C = 64; r0 = t * 64; c0 = 0;
    }
    int tid = threadIdx.x;
    int rr = tid >> 4, cc = (tid & 15) * 4;
    #pragma unroll
    for (int it = 0; it < 4; ++it) {
        int r = it * 16 + rr;
        float4 v = *(const float4*)(src + (size_t)(r0 + r) * C + c0 + cc);
        tl[cc + 0][r] = f2bf(v.x); tl[cc + 1][r] = f2bf(v.y);
        tl[cc + 2][r] = f2bf(v.z); tl[cc + 3][r] = f2bf(v.w);
    }
    __syncthreads();
    #pragma unroll
    for (int it = 0; it < 4; ++it) {
        int crow = it * 16 + rr;
        ushort4 o;
        o.x = tl[crow][cc + 0]; o.y = tl[crow][cc + 1];
        o.z = tl[crow][cc + 2]; o.w = tl[crow][cc + 3];
        *(ushort4*)(dst + (size_t)(c0 + crow) * R + r0 + cc) = o;
    }
}

// ---------------- SpMM (unroll 8/4/1) ----------------
__global__ void spmm_bf16(const int* __restrict__ rowptr, const int* __restrict__ col,
                          const float* __restrict__ wv, const u16* __restrict__ xb,
                          u16* __restrict__ outb, int n) {
    int row = blockIdx.x * 4 + (threadIdx.x >> 6);
    if (row >= n) return;
    int lane = threadIdx.x & 63;
    int p0 = rowptr[row], p1 = rowptr[row + 1];
    float a0 = 0.f, a1 = 0.f, a2 = 0.f, a3 = 0.f;
    int p = p0;
    for (; p + 8 <= p1; p += 8) {
        int   c[8]; float wt[8]; ushort4 v[8];
        #pragma unroll
        for (int u = 0; u < 8; ++u) { c[u] = col[p + u]; wt[u] = wv[p + u]; }
        #pragma unroll
        for (int u = 0; u < 8; ++u)
            v[u] = *(const ushort4*)(xb + (size_t)c[u] * FD + lane * 4);
        #pragma unroll
        for (int u = 0; u < 8; ++u) {
            a0 += wt[u] * bf2f(v[u].x); a1 += wt[u] * bf2f(v[u].y);
            a2 += wt[u] * bf2f(v[u].z); a3 += wt[u] * bf2f(v[u].w);
        }
    }
    for (; p + 4 <= p1; p += 4) {
        int   c[4]; float wt[4]; ushort4 v[4];
        #pragma unroll
        for (int u = 0; u < 4; ++u) { c[u] = col[p + u]; wt[u] = wv[p + u]; }
        #pragma unroll
        for (int u = 0; u < 4; ++u)
            v[u] = *(const ushort4*)(xb + (size_t)c[u] * FD + lane * 4);
        #pragma unroll
        for (int u = 0; u < 4; ++u) {
            a0 += wt[u] * bf2f(v[u].x); a1 += wt[u] * bf2f(v[u].y);
            a2 += wt[u] * bf2f(v[u].z); a3 += wt[u] * bf2f(v[u].w);
        }
    }
    for (; p < p1; ++p) {
        int c = col[p];
        float wt = wv[p];
        ushort4 v = *(const ushort4*)(xb + (size_t)c * FD + lane * 4);
        a0 += wt * bf2f(v.x); a1 += wt * bf2f(v.y);
        a2 += wt * bf2f(v.z); a3 += wt * bf2f(v.w);
    }
    ushort4 o;
    o.x = f2bf(a0); o.y = f2bf(a1); o.z = f2bf(a2); o.w = f2bf(a3);
    *(ushort4*)(outb + (size_t)row * FD + lane * 4) = o;
}

// ---------------- fused MFMA GEMM ----------------
// LDS (32 KB): in[64 r][256 k] bf16, byte(r,k16) = r*512 + ((k16^(r&7))<<4);
// reused for t[64 r][256 j] with the same swizzle. W read direct from global.
__launch_bounds__(256, 3)
__global__ void fused_mfma(const u16* __restrict__ xb, const u16* __restrict__ agg1b,
                           const u16* __restrict__ agg2b, const u16* __restrict__ WkT,
                           const float* __restrict__ b0, const float* __restrict__ b1,
                           const float* __restrict__ b2, const u16* __restrict__ WcT,
                           const float* __restrict__ bc, float* __restrict__ out, int n) {
    __shared__ __align__(16) char inT[32768];
    const int tid = threadIdx.x;
    const int w = tid >> 6, l = tid & 63;
    const int l4 = l >> 4, lm = l & 15;
    const int row0 = blockIdx.x * 64;

    f32x4 oacc[4];
    #pragma unroll
    for (int am = 0; am < 4; ++am) oacc[am] = (f32x4)(0.f);

    for (int k = 0; k < 3; ++k) {
        const u16* inb = (k == 0) ? xb : (k == 1) ? agg1b : agg2b;
        const u16* WT  = WkT + (size_t)k * 65536;
        const float* bk = (k == 0) ? b0 : (k == 1) ? b1 : b2;

        // stage in-tile: linear LDS dest, pre-swizzled global source (rule #21)
        #pragma unroll
        for (int c = 0; c < 8; ++c) {
            int Lb = w * 8192 + c * 1024 + l * 16;
            int r  = Lb >> 9;
            int s  = (Lb >> 4) & 31;
            int k16 = s ^ (r & 7);
            int gr = row0 + r; if (gr > n - 1) gr = n - 1;
            gll16(inb + (size_t)gr * FD + k16 * 8, inT + w * 8192 + c * 1024);
        }
        WVM0();
        BAR();

        // ---- stage B: t^T = Wk^T @ in^T, W frags direct from global (L2) ----
        f32x4 acc[4][4];
        #pragma unroll
        for (int jm = 0; jm < 4; ++jm)
            #pragma unroll
            for (int rn = 0; rn < 4; ++rn) acc[jm][rn] = (f32x4)(0.f);

        #pragma unroll
        for (int kk = 0; kk < 8; ++kk) {
            frag_ab a[4], bfr[4];
            #pragma unroll
            for (int jm = 0; jm < 4; ++jm)
                a[jm] = *(const frag_ab*)(WT + (size_t)(w * 64 + jm * 16 + lm) * FD + kk * 32 + 8 * l4);
            #pragma unroll
            for (int rn = 0; rn < 4; ++rn) {
                int r = rn * 16 + lm;
                bfr[rn] = *(const frag_ab*)(inT + r * 512 + (((kk * 4 + l4) ^ (r & 7)) << 4));
            }
            #pragma unroll
            for (int jm = 0; jm < 4; ++jm)
                #pragma unroll
                for (int rn = 0; rn < 4; ++rn)
                    acc[jm][rn] = __builtin_amdgcn_mfma_f32_16x16x32_bf16(a[jm], bfr[rn], acc[jm][rn], 0, 0, 0);
        }
        WLG0();
        BAR();   // all waves done reading in-tile; safe to overwrite with t

        // ---- bias + relu + pack t into inT ----
        #pragma unroll
        for (int jm = 0; jm < 4; ++jm) {
            float4 bb = *(const float4*)(bk + w * 64 + jm * 16 + l4 * 4);
            #pragma unroll
            for (int rn = 0; rn < 4; ++rn) {
                f32x4 v = acc[jm][rn];
                ushort4 p;
                p.x = f2bf(fmaxf(v[0] + bb.x, 0.f));
                p.y = f2bf(fmaxf(v[1] + bb.y, 0.f));
                p.z = f2bf(fmaxf(v[2] + bb.z, 0.f));
                p.w = f2bf(fmaxf(v[3] + bb.w, 0.f));
                int r = rn * 16 + lm;
                int j = w * 64 + jm * 16 + l4 * 4;
                *(ushort4*)(inT + r * 512 + (((j >> 3) ^ (r & 7)) << 4) + (j & 7) * 2) = p;
            }
        }
        WLG0();  // pack writes committed
        BAR();

        // ---- stage C: out^T += WcT_k @ t^T (WcT direct from global) ----
        const int rr = w * 16 + lm;
        #pragma unroll
        for (int kk = 0; kk < 8; ++kk) {
            frag_ab bfr = *(const frag_ab*)(inT + rr * 512 + (((kk * 4 + l4) ^ (rr & 7)) << 4));
            #pragma unroll
            for (int am = 0; am < 4; ++am) {
                frag_ab afr = *(const frag_ab*)(WcT + (size_t)(am * 16 + lm) * 768 + k * 256 + kk * 32 + 8 * l4);
                oacc[am] = __builtin_amdgcn_mfma_f32_16x16x32_bf16(afr, bfr, oacc[am], 0, 0, 0);
            }
        }
        WLG0();  // t reads done before next hop overwrites inT
        BAR();
    }

    int gr = row0 + w * 16 + lm;
    if (gr < n) {
        #pragma unroll
        for (int am = 0; am < 4; ++am) {
            float4 bb = *(const float4*)(bc + am * 16 + l4 * 4);
            float4 o;
            o.x = oacc[am][0] + bb.x;
            o.y = oacc[am][1] + bb.y;
            o.z = oacc[am][2] + bb.z;
            o.w = oacc[am][3] + bb.w;
            *(float4*)(out + (size_t)gr * CO + am * 16 + l4 * 4) = o;
        }
    }
}

extern "C" void kernel_launch(void* const* d_in, const int* in_sizes, int n_in,
                              void* d_out, int out_size, void* d_ws, size_t ws_size,
                              hipStream_t stream) {
    const float* x  = (const float*)d_in[0];
    const int*   ei = (const int*)d_in[1];
    const float* W0 = (const float*)d_in[3];
    const float* b0 = (const float*)d_in[4];
    const float* W1 = (const float*)d_in[5];
    const float* b1 = (const float*)d_in[6];
    const float* W2 = (const float*)d_in[7];
    const float* b2 = (const float*)d_in[8];
    const float* Wc = (const float*)d_in[9];
    const float* bc = (const float*)d_in[10];
    float* out = (float*)d_out;

    const int n  = in_sizes[0] / FD;   // 50000
    const int e  = in_sizes[1] / 2;    // 400000
    const int ep = e + n;
    const int nb = (n + SB - 1) / SB;

    char* ws = (char*)d_ws;
    size_t o = 0;
    auto take = [&](size_t nbytes) -> char* {
        char* p = ws + o;
        o += (nbytes + 255) & ~(size_t)255;
        return p;
    };
    int*   deg    = (int*)  take((size_t)n * 4);
    int*   fill   = (int*)  take((size_t)n * 4);
    float* dis    = (float*)take((size_t)n * 4);
    int*   rowptr = (int*)  take((size_t)(n + 1) * 4);
    int*   bsum   = (int*)  take((size_t)(nb + 1) * 4);
    int*   bscan  = (int*)  take((size_t)(nb + 1) * 4);
    int*   col    = (int*)  take((size_t)ep * 4);
    float* wv     = (float*)take((size_t)ep * 4);
    u16*   xb     = (u16*)  take((size_t)n * FD * 2);
    u16*   agg1b  = (u16*)  take((size_t)n * FD * 2);
    u16*   agg2b  = (u16*)  take((size_t)n * FD * 2);
    u16*   WkT    = (u16*)  take((size_t)3 * FD * FD * 2);
    u16*   WcT    = (u16*)  take((size_t)CO * 3 * FD * 2);
    (void)ws_size; (void)n_in; (void)out_size;

    init_kernel <<<(n + 255) / 256, 256, 0, stream>>>(deg, fill, n);
    count_kernel<<<(e + 255) / 256, 256, 0, stream>>>(ei, deg, e);
    scan1       <<<nb, SB, 0, stream>>>(deg, rowptr, bsum, dis, n);
    scan2       <<<1, 128, 0, stream>>>(bsum, bscan, nb);
    scan3       <<<(n + 256) / 256, 256, 0, stream>>>(rowptr, bscan, n, nb);
    fill_kernel <<<(ep + 255) / 256, 256, 0, stream>>>(ei, dis, rowptr, fill, col, wv, e, n);

    const int total4 = n * FD / 4;
    conv_kernel  <<<(total4 + 255) / 256, 256, 0, stream>>>(x, xb, total4);
    wtrans_kernel<<<60, 256, 0, stream>>>(W0, W1, W2, Wc, WkT, WcT);

    spmm_bf16<<<(n + 3) / 4, 256, 0, stream>>>(rowptr, col, wv, xb, agg1b, n);
    spmm_bf16<<<(n + 3) / 4, 256, 0, stream>>>(rowptr, col, wv, agg1b, agg2b, n);

    fused_mfma<<<(n + 63) / 64, 256, 0, stream>>>(xb, agg1b, agg2b, WkT, b0, b1, b2,
                                                  WcT, bc, out, n);
}

// Round 5
// 264.899 us; speedup vs baseline: 1.0152x; 1.0152x over previous
//
#include <hip/hip_runtime.h>

// H2GCN: CSR build -> bf16 SpMM x2 (unroll-16) -> gemm1 (m97-style 128x128,
// T = relu(IN3 @ Wk + bk), bf16) -> gemm2 (out = T' @ WcT + bc, no-LDS).

#define FD 256    // D == H == 256
#define CO 64     // out channels
#define SB 512    // scan block
#define MT1 391   // gemm1 M-tiles per segment: 391*128 = 50048
#define PS (50048 * 256)   // T panel stride (elems)

using frag_ab = __attribute__((ext_vector_type(8))) short;  // 8 bf16
using f32x4   = __attribute__((ext_vector_type(4))) float;
typedef unsigned short u16;
typedef unsigned int   u32;

__device__ __forceinline__ u16 f2bf(float f) {
    u32 u = __builtin_bit_cast(u32, f);
    return (u16)((u + 0x7FFFu + ((u >> 16) & 1u)) >> 16);
}
__device__ __forceinline__ float bf2f(u16 u) {
    u32 v = ((u32)u) << 16;
    return __builtin_bit_cast(float, v);
}

__device__ __forceinline__ void gll16(const void* g, void* l) {
    __builtin_amdgcn_global_load_lds(
        (const __attribute__((address_space(1))) u32*)g,
        (__attribute__((address_space(3))) u32*)l, 16, 0, 0);
}

#define BAR()  __builtin_amdgcn_s_barrier()
#define WLG0() asm volatile("s_waitcnt lgkmcnt(0)" ::: "memory")
#define WVM0() asm volatile("s_waitcnt vmcnt(0)" ::: "memory")

// ---------------- CSR build ----------------
__global__ void init_kernel(int* deg, int* fill, int n) {
    int i = blockIdx.x * blockDim.x + threadIdx.x;
    if (i < n) { deg[i] = 1; fill[i] = 0; }
}
__global__ void count_kernel(const int* __restrict__ ei0, int* deg, int e) {
    int i = blockIdx.x * blockDim.x + threadIdx.x;
    if (i < e) atomicAdd(&deg[ei0[i]], 1);
}
__global__ void scan1(const int* __restrict__ deg, int* __restrict__ rowptr,
                      int* __restrict__ bsum, float* __restrict__ dis, int n) {
    __shared__ int sh[SB];
    int tid = threadIdx.x;
    int i = blockIdx.x * SB + tid;
    int v = (i < n) ? deg[i] : 0;
    if (i < n) dis[i] = rsqrtf((float)v);
    sh[tid] = v;
    __syncthreads();
    for (int off = 1; off < SB; off <<= 1) {
        int add = (tid >= off) ? sh[tid - off] : 0;
        __syncthreads();
        sh[tid] += add;
        __syncthreads();
    }
    if (i < n) rowptr[i] = sh[tid] - v;
    if (tid == SB - 1) bsum[blockIdx.x] = sh[tid];
}
__global__ void scan2(const int* __restrict__ bsum, int* __restrict__ bscan, int nb) {
    __shared__ int sh[128];
    int tid = threadIdx.x;
    int v = (tid < nb) ? bsum[tid] : 0;
    sh[tid] = v;
    __syncthreads();
    for (int off = 1; off < 128; off <<= 1) {
        int add = (tid >= off) ? sh[tid - off] : 0;
        __syncthreads();
        sh[tid] += add;
        __syncthreads();
    }
    if (tid < nb) bscan[tid] = sh[tid] - v;
    if (tid == nb - 1) bscan[nb] = sh[tid];
}
__global__ void scan3(int* rowptr, const int* __restrict__ bscan, int n, int nb) {
    int i = blockIdx.x * 256 + threadIdx.x;
    if (i < n) rowptr[i] += bscan[i / SB];
    if (i == n) rowptr[n] = bscan[nb];
}
__global__ void fill_kernel(const int* __restrict__ ei, const float* __restrict__ dis,
                            const int* __restrict__ rowptr, int* fill,
                            int* __restrict__ col, float* __restrict__ wv, int e, int n) {
    int i = blockIdx.x * blockDim.x + threadIdx.x;
    if (i >= e + n) return;
    int r, c;
    if (i < e) { r = ei[i]; c = ei[e + i]; }
    else       { r = i - e; c = r; }
    float w = dis[r] * dis[c];
    int pos = rowptr[r] + atomicAdd(&fill[r], 1);
    col[pos] = c;
    wv[pos]  = w;
}

// ---------------- dtype prep ----------------
__global__ void conv_kernel(const float* __restrict__ x, u16* __restrict__ xb, int total4) {
    int i = blockIdx.x * blockDim.x + threadIdx.x;
    if (i < total4) {
        float4 v = ((const float4*)x)[i];
        ushort4 o;
        o.x = f2bf(v.x); o.y = f2bf(v.y); o.z = f2bf(v.z); o.w = f2bf(v.w);
        ((ushort4*)xb)[i] = o;
    }
}
__global__ void wtrans_kernel(const float* __restrict__ W0, const float* __restrict__ W1,
                              const float* __restrict__ W2, const float* __restrict__ Wc,
                              u16* __restrict__ WkT, u16* __restrict__ WcT) {
    __shared__ u16 tl[64][65];
    int b = blockIdx.x;
    const float* src; u16* dst; int R, C, r0, c0;
    if (b < 48) {
        int k = b >> 4, t = b & 15;
        src = (k == 0) ? W0 : (k == 1) ? W1 : W2;
        dst = WkT + k * 65536;
        R = 256; C = 256; r0 = (t >> 2) * 64; c0 = (t & 3) * 64;
    } else {
        int t = b - 48;
        src = Wc; dst = WcT;
        R = 768; C = 64; r0 = t * 64; c0 = 0;
    }
    int tid = threadIdx.x;
    int rr = tid >> 4, cc = (tid & 15) * 4;
    #pragma unroll
    for (int it = 0; it < 4; ++it) {
        int r = it * 16 + rr;
        float4 v = *(const float4*)(src + (size_t)(r0 + r) * C + c0 + cc);
        tl[cc + 0][r] = f2bf(v.x); tl[cc + 1][r] = f2bf(v.y);
        tl[cc + 2][r] = f2bf(v.z); tl[cc + 3][r] = f2bf(v.w);
    }
    __syncthreads();
    #pragma unroll
    for (int it = 0; it < 4; ++it) {
        int crow = it * 16 + rr;
        ushort4 o;
        o.x = tl[crow][cc + 0]; o.y = tl[crow][cc + 1];
        o.z = tl[crow][cc + 2]; o.w = tl[crow][cc + 3];
        *(ushort4*)(dst + (size_t)(c0 + crow) * R + r0 + cc) = o;
    }
}

// ---------------- SpMM (unroll 16/4/1) ----------------
__global__ void spmm_bf16(const int* __restrict__ rowptr, const int* __restrict__ col,
                          const float* __restrict__ wv, const u16* __restrict__ xb,
                          u16* __restrict__ outb, int n) {
    int row = blockIdx.x * 4 + (threadIdx.x >> 6);
    if (row >= n) return;
    int lane = threadIdx.x & 63;
    int p0 = rowptr[row], p1 = rowptr[row + 1];
    float a0 = 0.f, a1 = 0.f, a2 = 0.f, a3 = 0.f;
    int p = p0;
    for (; p + 16 <= p1; p += 16) {
        int   c[16]; float wt[16]; ushort4 v[16];
        #pragma unroll
        for (int u = 0; u < 16; ++u) { c[u] = col[p + u]; wt[u] = wv[p + u]; }
        #pragma unroll
        for (int u = 0; u < 16; ++u)
            v[u] = *(const ushort4*)(xb + (size_t)c[u] * FD + lane * 4);
        #pragma unroll
        for (int u = 0; u < 16; ++u) {
            a0 += wt[u] * bf2f(v[u].x); a1 += wt[u] * bf2f(v[u].y);
            a2 += wt[u] * bf2f(v[u].z); a3 += wt[u] * bf2f(v[u].w);
        }
    }
    for (; p + 4 <= p1; p += 4) {
        int   c[4]; float wt[4]; ushort4 v[4];
        #pragma unroll
        for (int u = 0; u < 4; ++u) { c[u] = col[p + u]; wt[u] = wv[p + u]; }
        #pragma unroll
        for (int u = 0; u < 4; ++u)
            v[u] = *(const ushort4*)(xb + (size_t)c[u] * FD + lane * 4);
        #pragma unroll
        for (int u = 0; u < 4; ++u) {
            a0 += wt[u] * bf2f(v[u].x); a1 += wt[u] * bf2f(v[u].y);
            a2 += wt[u] * bf2f(v[u].z); a3 += wt[u] * bf2f(v[u].w);
        }
    }
    for (; p < p1; ++p) {
        int c = col[p];
        float wt = wv[p];
        ushort4 v = *(const ushort4*)(xb + (size_t)c * FD + lane * 4);
        a0 += wt * bf2f(v.x); a1 += wt * bf2f(v.y);
        a2 += wt * bf2f(v.z); a3 += wt * bf2f(v.w);
    }
    ushort4 o;
    o.x = f2bf(a0); o.y = f2bf(a1); o.z = f2bf(a2); o.w = f2bf(a3);
    *(ushort4*)(outb + (size_t)row * FD + lane * 4) = o;
}

// ---------------- gemm1: T[seg][r][j] = relu(in_seg @ Wk_seg + bk_seg) ----------------
// m97 structure: 128x128 tile, BK=64, LDS A-tile 16KB + B-tile 16KB (XOR-swizzled
// via pre-swizzled global source), 2 barriers / K-step, 4 K-steps.
__launch_bounds__(256, 3)
__global__ void gemm1(const u16* __restrict__ xb, const u16* __restrict__ agg1b,
                      const u16* __restrict__ agg2b, const u16* __restrict__ WkT,
                      const float* __restrict__ b0, const float* __restrict__ b1,
                      const float* __restrict__ b2, u16* __restrict__ T, int n) {
    __shared__ __align__(16) char lds[32768];   // A [0,16K), B [16K,32K)
    char* lA = lds;
    char* lB = lds + 16384;

    const int tid = threadIdx.x;
    const int w = tid >> 6, l = tid & 63;
    const int l4 = l >> 4, lm = l & 15;
    const int mq = w & 1, nq = w >> 1;          // wave quadrant

    int bid = blockIdx.x;
    const int nt  = bid & 1;          // N-tile (0,1)
    int rest = bid >> 1;
    const int mt  = rest % MT1;
    const int seg = rest / MT1;       // hop 0..2
    const int row0 = mt * 128;
    const int n0   = nt * 128;

    const u16* inb = (seg == 0) ? xb : (seg == 1) ? agg1b : agg2b;
    const u16* WT  = WkT + (size_t)seg * 65536;
    const float* bk = (seg == 0) ? b0 : (seg == 1) ? b1 : b2;

    f32x4 acc[4][4];
    #pragma unroll
    for (int jm = 0; jm < 4; ++jm)
        #pragma unroll
        for (int rn = 0; rn < 4; ++rn) acc[jm][rn] = (f32x4)(0.f);

    for (int kt = 0; kt < 4; ++kt) {
        WLG0();                        // my frag reads of lds done
        BAR();                         // everyone's done -> safe to restage
        #pragma unroll
        for (int c = 0; c < 4; ++c) {  // A-tile: in rows
            int L = w * 1024 + c * 4096 + l * 16;
            int r = L >> 7, s = (L >> 4) & 7;
            int k16 = s ^ (r & 7);
            int gr = row0 + r; if (gr > n - 1) gr = n - 1;
            gll16(inb + (size_t)gr * FD + kt * 64 + k16 * 8, lA + w * 1024 + c * 4096);
        }
        #pragma unroll
        for (int c = 0; c < 4; ++c) {  // B-tile: WkT rows (t-cols)
            int L = w * 1024 + c * 4096 + l * 16;
            int r = L >> 7, s = (L >> 4) & 7;
            int k16 = s ^ (r & 7);
            gll16(WT + (size_t)(n0 + r) * FD + kt * 64 + k16 * 8, lB + w * 1024 + c * 4096);
        }
        WVM0();
        BAR();

        #pragma unroll
        for (int kk2 = 0; kk2 < 2; ++kk2) {
            frag_ab af[4], bf_[4];
            #pragma unroll
            for (int jm = 0; jm < 4; ++jm) {
                int rB = nq * 64 + jm * 16 + lm;
                af[jm] = *(const frag_ab*)(lB + rB * 128 + (((kk2 * 4 + l4) ^ (rB & 7)) << 4));
            }
            #pragma unroll
            for (int rn = 0; rn < 4; ++rn) {
                int rA = mq * 64 + rn * 16 + lm;
                bf_[rn] = *(const frag_ab*)(lA + rA * 128 + (((kk2 * 4 + l4) ^ (rA & 7)) << 4));
            }
            #pragma unroll
            for (int jm = 0; jm < 4; ++jm)
                #pragma unroll
                for (int rn = 0; rn < 4; ++rn)
                    acc[jm][rn] = __builtin_amdgcn_mfma_f32_16x16x32_bf16(af[jm], bf_[rn], acc[jm][rn], 0, 0, 0);
        }
    }

    // epilogue: T[seg][r][j] = relu(acc + bk[j]) as bf16; lane's 4 j contiguous
    u16* Tp = T + (size_t)seg * PS;
    #pragma unroll
    for (int jm = 0; jm < 4; ++jm) {
        int j = n0 + nq * 64 + jm * 16 + l4 * 4;
        float4 bb = *(const float4*)(bk + j);
        #pragma unroll
        for (int rn = 0; rn < 4; ++rn) {
            int r = row0 + mq * 64 + rn * 16 + lm;    // < 50048, in-panel
            f32x4 v = acc[jm][rn];
            ushort4 p;
            p.x = f2bf(fmaxf(v[0] + bb.x, 0.f));
            p.y = f2bf(fmaxf(v[1] + bb.y, 0.f));
            p.z = f2bf(fmaxf(v[2] + bb.z, 0.f));
            p.w = f2bf(fmaxf(v[3] + bb.w, 0.f));
            *(ushort4*)(Tp + (size_t)r * FD + j) = p;
        }
    }
}

// ---------------- gemm2: out[r][c] = sum_q T'[r][q] WcT[c][q] + bc[c] ----------------
// BM=64, N=64, K=768. No LDS, no barriers: lane lm reads its own T row,
// WcT fragments direct from L2. acc = 16 VGPR -> deep compiler pipelining.
__launch_bounds__(256)
__global__ void gemm2(const u16* __restrict__ T, const u16* __restrict__ WcT,
                      const float* __restrict__ bc, float* __restrict__ out, int n) {
    const int tid = threadIdx.x;
    const int w = tid >> 6, l = tid & 63;
    const int l4 = l >> 4, lm = l & 15;
    const int r = blockIdx.x * 64 + w * 16 + lm;   // my T row (< 50048, in-panel)

    f32x4 acc[4];
    #pragma unroll
    for (int am = 0; am < 4; ++am) acc[am] = (f32x4)(0.f);

    #pragma unroll
    for (int kt = 0; kt < 12; ++kt) {
        const int seg = kt >> 2, c0 = (kt & 3) * 64;
        const u16* tp = T + (size_t)seg * PS + (size_t)r * FD + c0;
        #pragma unroll
        for (int kk2 = 0; kk2 < 2; ++kk2) {
            frag_ab bfr = *(const frag_ab*)(tp + kk2 * 32 + l4 * 8);
            #pragma unroll
            for (int am = 0; am < 4; ++am) {
                frag_ab afr = *(const frag_ab*)(WcT + (size_t)(am * 16 + lm) * 768 + kt * 64 + kk2 * 32 + l4 * 8);
                acc[am] = __builtin_amdgcn_mfma_f32_16x16x32_bf16(afr, bfr, acc[am], 0, 0, 0);
            }
        }
    }

    if (r < n) {
        #pragma unroll
        for (int am = 0; am < 4; ++am) {
            float4 bb = *(const float4*)(bc + am * 16 + l4 * 4);
            float4 o;
            o.x = acc[am][0] + bb.x;
            o.y = acc[am][1] + bb.y;
            o.z = acc[am][2] + bb.z;
            o.w = acc[am][3] + bb.w;
            *(float4*)(out + (size_t)r * CO + am * 16 + l4 * 4) = o;
        }
    }
}

extern "C" void kernel_launch(void* const* d_in, const int* in_sizes, int n_in,
                              void* d_out, int out_size, void* d_ws, size_t ws_size,
                              hipStream_t stream) {
    const float* x  = (const float*)d_in[0];
    const int*   ei = (const int*)d_in[1];
    const float* W0 = (const float*)d_in[3];
    const float* b0 = (const float*)d_in[4];
    const float* W1 = (const float*)d_in[5];
    const float* b1 = (const float*)d_in[6];
    const float* W2 = (const float*)d_in[7];
    const float* b2 = (const float*)d_in[8];
    const float* Wc = (const float*)d_in[9];
    const float* bc = (const float*)d_in[10];
    float* out = (float*)d_out;

    const int n  = in_sizes[0] / FD;   // 50000
    const int e  = in_sizes[1] / 2;    // 400000
    const int ep = e + n;
    const int nb = (n + SB - 1) / SB;

    char* ws = (char*)d_ws;
    size_t o = 0;
    auto take = [&](size_t nbytes) -> char* {
        char* p = ws + o;
        o += (nbytes + 255) & ~(size_t)255;
        return p;
    };
    int*   deg    = (int*)  take((size_t)n * 4);
    int*   fill   = (int*)  take((size_t)n * 4);
    float* dis    = (float*)take((size_t)n * 4);
    int*   rowptr = (int*)  take((size_t)(n + 1) * 4);
    int*   bsum   = (int*)  take((size_t)(nb + 1) * 4);
    int*   bscan  = (int*)  take((size_t)(nb + 1) * 4);
    int*   col    = (int*)  take((size_t)ep * 4);
    float* wv     = (float*)take((size_t)ep * 4);
    u16*   xb     = (u16*)  take((size_t)n * FD * 2);
    u16*   agg1b  = (u16*)  take((size_t)n * FD * 2);
    u16*   agg2b  = (u16*)  take((size_t)n * FD * 2);
    u16*   WkT    = (u16*)  take((size_t)3 * FD * FD * 2);
    u16*   WcT    = (u16*)  take((size_t)CO * 3 * FD * 2);
    u16*   T      = (u16*)  take((size_t)3 * PS * 2);
    (void)ws_size; (void)n_in; (void)out_size;

    init_kernel <<<(n + 255) / 256, 256, 0, stream>>>(deg, fill, n);
    count_kernel<<<(e + 255) / 256, 256, 0, stream>>>(ei, deg, e);
    scan1       <<<nb, SB, 0, stream>>>(deg, rowptr, bsum, dis, n);
    scan2       <<<1, 128, 0, stream>>>(bsum, bscan, nb);
    scan3       <<<(n + 256) / 256, 256, 0, stream>>>(rowptr, bscan, n, nb);
    fill_kernel <<<(ep + 255) / 256, 256, 0, stream>>>(ei, dis, rowptr, fill, col, wv, e, n);

    const int total4 = n * FD / 4;
    conv_kernel  <<<(total4 + 255) / 256, 256, 0, stream>>>(x, xb, total4);
    wtrans_kernel<<<60, 256, 0, stream>>>(W0, W1, W2, Wc, WkT, WcT);

    spmm_bf16<<<(n + 3) / 4, 256, 0, stream>>>(rowptr, col, wv, xb, agg1b, n);
    spmm_bf16<<<(n + 3) / 4, 256, 0, stream>>>(rowptr, col, wv, agg1b, agg2b, n);

    gemm1<<<2 * MT1 * 3, 256, 0, stream>>>(xb, agg1b, agg2b, WkT, b0, b1, b2, T, n);
    gemm2<<<(n + 63) / 64, 256, 0, stream>>>(T, WcT, bc, out, n);
}

// Round 6
// 245.302 us; speedup vs baseline: 1.0963x; 1.0799x over previous
//
#include <hip/hip_runtime.h>

// H2GCN: CSR build -> bf16 SpMM x2 (2 rows/wave, 16B/lane) -> gemm1 (m97-style
// 128x128, T = relu(IN3 @ Wk + bk), bf16) -> gemm2 (out = T' @ WcT + bc,
// LDS-staged T tiles, counted vmcnt double-buffer).

#define FD 256    // D == H == 256
#define CO 64     // out channels
#define SB 512    // scan block
#define MT1 391   // gemm1 M-tiles per segment: 391*128 = 50048
#define PS (50048 * 256)   // T panel stride (elems)

using frag_ab = __attribute__((ext_vector_type(8))) short;  // 8 bf16
using f32x4   = __attribute__((ext_vector_type(4))) float;
typedef unsigned short u16;
typedef unsigned int   u32;

__device__ __forceinline__ u16 f2bf(float f) {
    u32 u = __builtin_bit_cast(u32, f);
    return (u16)((u + 0x7FFFu + ((u >> 16) & 1u)) >> 16);
}
__device__ __forceinline__ float bf2f(u16 u) {
    u32 v = ((u32)u) << 16;
    return __builtin_bit_cast(float, v);
}
__device__ __forceinline__ float bfl(u32 packed) {          // low bf16
    return __builtin_bit_cast(float, packed << 16);
}
__device__ __forceinline__ float bfh(u32 packed) {          // high bf16
    return __builtin_bit_cast(float, packed & 0xFFFF0000u);
}

__device__ __forceinline__ void gll16(const void* g, void* l) {
    __builtin_amdgcn_global_load_lds(
        (const __attribute__((address_space(1))) u32*)g,
        (__attribute__((address_space(3))) u32*)l, 16, 0, 0);
}

#define BAR()  __builtin_amdgcn_s_barrier()
#define WLG0() asm volatile("s_waitcnt lgkmcnt(0)" ::: "memory")
#define WVM0() asm volatile("s_waitcnt vmcnt(0)" ::: "memory")
#define WVM2() asm volatile("s_waitcnt vmcnt(2)" ::: "memory")

// ---------------- CSR build ----------------
__global__ void init_kernel(int* deg, int* fill, int n) {
    int i = blockIdx.x * blockDim.x + threadIdx.x;
    if (i < n) { deg[i] = 1; fill[i] = 0; }
}
__global__ void count_kernel(const int* __restrict__ ei0, int* deg, int e) {
    int i = blockIdx.x * blockDim.x + threadIdx.x;
    if (i < e) atomicAdd(&deg[ei0[i]], 1);
}
__global__ void scan1(const int* __restrict__ deg, int* __restrict__ rowptr,
                      int* __restrict__ bsum, float* __restrict__ dis, int n) {
    __shared__ int sh[SB];
    int tid = threadIdx.x;
    int i = blockIdx.x * SB + tid;
    int v = (i < n) ? deg[i] : 0;
    if (i < n) dis[i] = rsqrtf((float)v);
    sh[tid] = v;
    __syncthreads();
    for (int off = 1; off < SB; off <<= 1) {
        int add = (tid >= off) ? sh[tid - off] : 0;
        __syncthreads();
        sh[tid] += add;
        __syncthreads();
    }
    if (i < n) rowptr[i] = sh[tid] - v;
    if (tid == SB - 1) bsum[blockIdx.x] = sh[tid];
}
__global__ void scan2(const int* __restrict__ bsum, int* __restrict__ bscan, int nb) {
    __shared__ int sh[128];
    int tid = threadIdx.x;
    int v = (tid < nb) ? bsum[tid] : 0;
    sh[tid] = v;
    __syncthreads();
    for (int off = 1; off < 128; off <<= 1) {
        int add = (tid >= off) ? sh[tid - off] : 0;
        __syncthreads();
        sh[tid] += add;
        __syncthreads();
    }
    if (tid < nb) bscan[tid] = sh[tid] - v;
    if (tid == nb - 1) bscan[nb] = sh[tid];
}
__global__ void scan3(int* rowptr, const int* __restrict__ bscan, int n, int nb) {
    int i = blockIdx.x * 256 + threadIdx.x;
    if (i < n) rowptr[i] += bscan[i / SB];
    if (i == n) rowptr[n] = bscan[nb];
}
__global__ void fill_kernel(const int* __restrict__ ei, const float* __restrict__ dis,
                            const int* __restrict__ rowptr, int* fill,
                            int* __restrict__ col, float* __restrict__ wv, int e, int n) {
    int i = blockIdx.x * blockDim.x + threadIdx.x;
    if (i >= e + n) return;
    int r, c;
    if (i < e) { r = ei[i]; c = ei[e + i]; }
    else       { r = i - e; c = r; }
    float w = dis[r] * dis[c];
    int pos = rowptr[r] + atomicAdd(&fill[r], 1);
    col[pos] = c;
    wv[pos]  = w;
}

// ---------------- dtype prep ----------------
__global__ void conv_kernel(const float* __restrict__ x, u16* __restrict__ xb, int total4) {
    int i = blockIdx.x * blockDim.x + threadIdx.x;
    if (i < total4) {
        float4 v = ((const float4*)x)[i];
        ushort4 o;
        o.x = f2bf(v.x); o.y = f2bf(v.y); o.z = f2bf(v.z); o.w = f2bf(v.w);
        ((ushort4*)xb)[i] = o;
    }
}
__global__ void wtrans_kernel(const float* __restrict__ W0, const float* __restrict__ W1,
                              const float* __restrict__ W2, const float* __restrict__ Wc,
                              u16* __restrict__ WkT, u16* __restrict__ WcT) {
    __shared__ u16 tl[64][65];
    int b = blockIdx.x;
    const float* src; u16* dst; int R, C, r0, c0;
    if (b < 48) {
        int k = b >> 4, t = b & 15;
        src = (k == 0) ? W0 : (k == 1) ? W1 : W2;
        dst = WkT + k * 65536;
        R = 256; C = 256; r0 = (t >> 2) * 64; c0 = (t & 3) * 64;
    } else {
        int t = b - 48;
        src = Wc; dst = WcT;
        R = 768; C = 64; r0 = t * 64; c0 = 0;
    }
    int tid = threadIdx.x;
    int rr = tid >> 4, cc = (tid & 15) * 4;
    #pragma unroll
    for (int it = 0; it < 4; ++it) {
        int r = it * 16 + rr;
        float4 v = *(const float4*)(src + (size_t)(r0 + r) * C + c0 + cc);
        tl[cc + 0][r] = f2bf(v.x); tl[cc + 1][r] = f2bf(v.y);
        tl[cc + 2][r] = f2bf(v.z); tl[cc + 3][r] = f2bf(v.w);
    }
    __syncthreads();
    #pragma unroll
    for (int it = 0; it < 4; ++it) {
        int crow = it * 16 + rr;
        ushort4 o;
        o.x = tl[crow][cc + 0]; o.y = tl[crow][cc + 1];
        o.z = tl[crow][cc + 2]; o.w = tl[crow][cc + 3];
        *(ushort4*)(dst + (size_t)(c0 + crow) * R + r0 + cc) = o;
    }
}

// ---------------- SpMM: 2 rows per wave, 32 lanes x 16B each ----------------
__global__ void spmm_bf16(const int* __restrict__ rowptr, const int* __restrict__ col,
                          const float* __restrict__ wv, const u16* __restrict__ xb,
                          u16* __restrict__ outb, int n) {
    int tid = threadIdx.x;
    int lane = tid & 63;
    int row = blockIdx.x * 8 + ((tid >> 6) << 1) + (lane >> 5);
    if (row >= n) return;
    int l32 = lane & 31;
    int p0 = rowptr[row], p1 = rowptr[row + 1];
    float a[8];
    #pragma unroll
    for (int j = 0; j < 8; ++j) a[j] = 0.f;

    int p = p0;
    for (; p + 4 <= p1; p += 4) {
        int c[4]; float wt[4]; uint4 v[4];
        #pragma unroll
        for (int u = 0; u < 4; ++u) { c[u] = col[p + u]; wt[u] = wv[p + u]; }
        #pragma unroll
        for (int u = 0; u < 4; ++u)
            v[u] = *(const uint4*)(xb + (size_t)c[u] * FD + l32 * 8);
        #pragma unroll
        for (int u = 0; u < 4; ++u) {
            a[0] += wt[u] * bfl(v[u].x); a[1] += wt[u] * bfh(v[u].x);
            a[2] += wt[u] * bfl(v[u].y); a[3] += wt[u] * bfh(v[u].y);
            a[4] += wt[u] * bfl(v[u].z); a[5] += wt[u] * bfh(v[u].z);
            a[6] += wt[u] * bfl(v[u].w); a[7] += wt[u] * bfh(v[u].w);
        }
    }
    for (; p < p1; ++p) {
        int c = col[p];
        float wt = wv[p];
        uint4 v = *(const uint4*)(xb + (size_t)c * FD + l32 * 8);
        a[0] += wt * bfl(v.x); a[1] += wt * bfh(v.x);
        a[2] += wt * bfl(v.y); a[3] += wt * bfh(v.y);
        a[4] += wt * bfl(v.z); a[5] += wt * bfh(v.z);
        a[6] += wt * bfl(v.w); a[7] += wt * bfh(v.w);
    }
    uint4 o;
    o.x = (u32)f2bf(a[0]) | ((u32)f2bf(a[1]) << 16);
    o.y = (u32)f2bf(a[2]) | ((u32)f2bf(a[3]) << 16);
    o.z = (u32)f2bf(a[4]) | ((u32)f2bf(a[5]) << 16);
    o.w = (u32)f2bf(a[6]) | ((u32)f2bf(a[7]) << 16);
    *(uint4*)(outb + (size_t)row * FD + l32 * 8) = o;
}

// ---------------- gemm1: T[seg][r][j] = relu(in_seg @ Wk_seg + bk_seg) ----------------
// m97 structure: 128x128 tile, BK=64, LDS A-tile 16KB + B-tile 16KB (XOR-swizzled
// via pre-swizzled global source), 2 barriers / K-step, 4 K-steps.
__launch_bounds__(256, 3)
__global__ void gemm1(const u16* __restrict__ xb, const u16* __restrict__ agg1b,
                      const u16* __restrict__ agg2b, const u16* __restrict__ WkT,
                      const float* __restrict__ b0, const float* __restrict__ b1,
                      const float* __restrict__ b2, u16* __restrict__ T, int n) {
    __shared__ __align__(16) char lds[32768];   // A [0,16K), B [16K,32K)
    char* lA = lds;
    char* lB = lds + 16384;

    const int tid = threadIdx.x;
    const int w = tid >> 6, l = tid & 63;
    const int l4 = l >> 4, lm = l & 15;
    const int mq = w & 1, nq = w >> 1;          // wave quadrant

    int bid = blockIdx.x;
    const int nt  = bid & 1;          // N-tile (0,1)
    int rest = bid >> 1;
    const int mt  = rest % MT1;
    const int seg = rest / MT1;       // hop 0..2
    const int row0 = mt * 128;
    const int n0   = nt * 128;

    const u16* inb = (seg == 0) ? xb : (seg == 1) ? agg1b : agg2b;
    const u16* WT  = WkT + (size_t)seg * 65536;
    const float* bk = (seg == 0) ? b0 : (seg == 1) ? b1 : b2;

    f32x4 acc[4][4];
    #pragma unroll
    for (int jm = 0; jm < 4; ++jm)
        #pragma unroll
        for (int rn = 0; rn < 4; ++rn) acc[jm][rn] = (f32x4)(0.f);

    for (int kt = 0; kt < 4; ++kt) {
        WLG0();                        // my frag reads of lds done
        BAR();                         // everyone's done -> safe to restage
        #pragma unroll
        for (int c = 0; c < 4; ++c) {  // A-tile: in rows
            int L = w * 1024 + c * 4096 + l * 16;
            int r = L >> 7, s = (L >> 4) & 7;
            int k16 = s ^ (r & 7);
            int gr = row0 + r; if (gr > n - 1) gr = n - 1;
            gll16(inb + (size_t)gr * FD + kt * 64 + k16 * 8, lA + w * 1024 + c * 4096);
        }
        #pragma unroll
        for (int c = 0; c < 4; ++c) {  // B-tile: WkT rows (t-cols)
            int L = w * 1024 + c * 4096 + l * 16;
            int r = L >> 7, s = (L >> 4) & 7;
            int k16 = s ^ (r & 7);
            gll16(WT + (size_t)(n0 + r) * FD + kt * 64 + k16 * 8, lB + w * 1024 + c * 4096);
        }
        WVM0();
        BAR();

        #pragma unroll
        for (int kk2 = 0; kk2 < 2; ++kk2) {
            frag_ab af[4], bf_[4];
            #pragma unroll
            for (int jm = 0; jm < 4; ++jm) {
                int rB = nq * 64 + jm * 16 + lm;
                af[jm] = *(const frag_ab*)(lB + rB * 128 + (((kk2 * 4 + l4) ^ (rB & 7)) << 4));
            }
            #pragma unroll
            for (int rn = 0; rn < 4; ++rn) {
                int rA = mq * 64 + rn * 16 + lm;
                bf_[rn] = *(const frag_ab*)(lA + rA * 128 + (((kk2 * 4 + l4) ^ (rA & 7)) << 4));
            }
            #pragma unroll
            for (int jm = 0; jm < 4; ++jm)
                #pragma unroll
                for (int rn = 0; rn < 4; ++rn)
                    acc[jm][rn] = __builtin_amdgcn_mfma_f32_16x16x32_bf16(af[jm], bf_[rn], acc[jm][rn], 0, 0, 0);
        }
    }

    // epilogue: T[seg][r][j] = relu(acc + bk[j]) as bf16; lane's 4 j contiguous
    u16* Tp = T + (size_t)seg * PS;
    #pragma unroll
    for (int jm = 0; jm < 4; ++jm) {
        int j = n0 + nq * 64 + jm * 16 + l4 * 4;
        float4 bb = *(const float4*)(bk + j);
        #pragma unroll
        for (int rn = 0; rn < 4; ++rn) {
            int r = row0 + mq * 64 + rn * 16 + lm;    // < 50048, in-panel
            f32x4 v = acc[jm][rn];
            ushort4 p;
            p.x = f2bf(fmaxf(v[0] + bb.x, 0.f));
            p.y = f2bf(fmaxf(v[1] + bb.y, 0.f));
            p.z = f2bf(fmaxf(v[2] + bb.z, 0.f));
            p.w = f2bf(fmaxf(v[3] + bb.w, 0.f));
            *(ushort4*)(Tp + (size_t)r * FD + j) = p;
        }
    }
}

// ---------------- gemm2: out[r][c] = sum_q T'[r][q] WcT[c][q] + bc[c] ----------------
// BM=64, K=768 in 12 steps of 64. T-tile staged via global_load_lds into a
// 2x8KB double buffer with counted vmcnt(2); WcT fragments direct from L2.
__launch_bounds__(256, 4)
__global__ void gemm2(const u16* __restrict__ T, const u16* __restrict__ WcT,
                      const float* __restrict__ bc, float* __restrict__ out, int n) {
    __shared__ __align__(16) char lds[16384];   // 2 x 8KB T-tile buffers
    const int tid = threadIdx.x;
    const int w = tid >> 6, l = tid & 63;
    const int l4 = l >> 4, lm = l & 15;
    const int row0 = blockIdx.x * 64;

    f32x4 acc[4];
    #pragma unroll
    for (int am = 0; am < 4; ++am) acc[am] = (f32x4)(0.f);

    auto stage = [&](int kt, char* buf) {
        const int seg = kt >> 2, c0 = (kt & 3) * 64;
        #pragma unroll
        for (int i = 0; i < 2; ++i) {
            int L = tid * 16 + i * 4096;
            int r = L >> 7, c8 = (L >> 4) & 7;
            gll16(T + (size_t)seg * PS + (size_t)(row0 + r) * FD + c0 + (c8 ^ (r & 7)) * 8,
                  buf + w * 1024 + l * 16 + i * 4096);
        }
    };

    stage(0, lds);
    const int rr = w * 16 + lm;
    #pragma unroll
    for (int kt = 0; kt < 12; ++kt) {
        char* cur = lds + (kt & 1) * 8192;
        if (kt < 11) {
            stage(kt + 1, lds + ((kt + 1) & 1) * 8192);
            WVM2();                    // cur's 2 loads landed; next 2 in flight
        } else {
            WVM0();
        }
        BAR();
        #pragma unroll
        for (int kk2 = 0; kk2 < 2; ++kk2) {
            frag_ab bfr = *(const frag_ab*)(cur + rr * 128 + (((kk2 * 4 + l4) ^ (rr & 7)) << 4));
            #pragma unroll
            for (int am = 0; am < 4; ++am) {
                frag_ab afr = *(const frag_ab*)(WcT + (size_t)(am * 16 + lm) * 768 + kt * 64 + kk2 * 32 + l4 * 8);
                acc[am] = __builtin_amdgcn_mfma_f32_16x16x32_bf16(afr, bfr, acc[am], 0, 0, 0);
            }
        }
        WLG0();                        // my LDS frag reads complete
        BAR();                         // all waves done with cur -> restage ok
    }

    int r = row0 + rr;
    if (r < n) {
        #pragma unroll
        for (int am = 0; am < 4; ++am) {
            float4 bb = *(const float4*)(bc + am * 16 + l4 * 4);
            float4 o;
            o.x = acc[am][0] + bb.x;
            o.y = acc[am][1] + bb.y;
            o.z = acc[am][2] + bb.z;
            o.w = acc[am][3] + bb.w;
            *(float4*)(out + (size_t)r * CO + am * 16 + l4 * 4) = o;
        }
    }
}

extern "C" void kernel_launch(void* const* d_in, const int* in_sizes, int n_in,
                              void* d_out, int out_size, void* d_ws, size_t ws_size,
                              hipStream_t stream) {
    const float* x  = (const float*)d_in[0];
    const int*   ei = (const int*)d_in[1];
    const float* W0 = (const float*)d_in[3];
    const float* b0 = (const float*)d_in[4];
    const float* W1 = (const float*)d_in[5];
    const float* b1 = (const float*)d_in[6];
    const float* W2 = (const float*)d_in[7];
    const float* b2 = (const float*)d_in[8];
    const float* Wc = (const float*)d_in[9];
    const float* bc = (const float*)d_in[10];
    float* out = (float*)d_out;

    const int n  = in_sizes[0] / FD;   // 50000
    const int e  = in_sizes[1] / 2;    // 400000
    const int ep = e + n;
    const int nb = (n + SB - 1) / SB;

    char* ws = (char*)d_ws;
    size_t o = 0;
    auto take = [&](size_t nbytes) -> char* {
        char* p = ws + o;
        o += (nbytes + 255) & ~(size_t)255;
        return p;
    };
    int*   deg    = (int*)  take((size_t)n * 4);
    int*   fill   = (int*)  take((size_t)n * 4);
    float* dis    = (float*)take((size_t)n * 4);
    int*   rowptr = (int*)  take((size_t)(n + 1) * 4);
    int*   bsum   = (int*)  take((size_t)(nb + 1) * 4);
    int*   bscan  = (int*)  take((size_t)(nb + 1) * 4);
    int*   col    = (int*)  take((size_t)ep * 4);
    float* wv     = (float*)take((size_t)ep * 4);
    u16*   xb     = (u16*)  take((size_t)n * FD * 2);
    u16*   agg1b  = (u16*)  take((size_t)n * FD * 2);
    u16*   agg2b  = (u16*)  take((size_t)n * FD * 2);
    u16*   WkT    = (u16*)  take((size_t)3 * FD * FD * 2);
    u16*   WcT    = (u16*)  take((size_t)CO * 3 * FD * 2);
    u16*   T      = (u16*)  take((size_t)3 * PS * 2);
    (void)ws_size; (void)n_in; (void)out_size;

    init_kernel <<<(n + 255) / 256, 256, 0, stream>>>(deg, fill, n);
    count_kernel<<<(e + 255) / 256, 256, 0, stream>>>(ei, deg, e);
    scan1       <<<nb, SB, 0, stream>>>(deg, rowptr, bsum, dis, n);
    scan2       <<<1, 128, 0, stream>>>(bsum, bscan, nb);
    scan3       <<<(n + 256) / 256, 256, 0, stream>>>(rowptr, bscan, n, nb);
    fill_kernel <<<(ep + 255) / 256, 256, 0, stream>>>(ei, dis, rowptr, fill, col, wv, e, n);

    const int total4 = n * FD / 4;
    conv_kernel  <<<(total4 + 255) / 256, 256, 0, stream>>>(x, xb, total4);
    wtrans_kernel<<<60, 256, 0, stream>>>(W0, W1, W2, Wc, WkT, WcT);

    spmm_bf16<<<(n + 7) / 8, 256, 0, stream>>>(rowptr, col, wv, xb, agg1b, n);
    spmm_bf16<<<(n + 7) / 8, 256, 0, stream>>>(rowptr, col, wv, agg1b, agg2b, n);

    gemm1<<<2 * MT1 * 3, 256, 0, stream>>>(xb, agg1b, agg2b, WkT, b0, b1, b2, T, n);
    gemm2<<<(n + 63) / 64, 256, 0, stream>>>(T, WcT, bc, out, n);
}

// Round 7
// 221.688 us; speedup vs baseline: 1.2130x; 1.1065x over previous
//
#include <hip/hip_runtime.h>

// H2GCN: CSR build -> bf16 SpMM x2 (2 rows/wave, 16B/lane, unroll-8) ->
// gemm1 (m97-style 128x128, T = relu(IN3 @ Wk + bk), bf16) ->
// gemm2-v3 (out = T' @ WcT + bc): T fragments preloaded to registers (24 x 16B
// per lane, deep MLP), WcT slices LDS ping-pong via global_load_lds.

#define FD 256    // D == H == 256
#define CO 64     // out channels
#define SB 512    // scan block
#define MT1 391   // gemm1 M-tiles per segment: 391*128 = 50048
#define PS (50048 * 256)   // T panel stride (elems)

using frag_ab = __attribute__((ext_vector_type(8))) short;  // 8 bf16
using f32x4   = __attribute__((ext_vector_type(4))) float;
typedef unsigned short u16;
typedef unsigned int   u32;

__device__ __forceinline__ u16 f2bf(float f) {
    u32 u = __builtin_bit_cast(u32, f);
    return (u16)((u + 0x7FFFu + ((u >> 16) & 1u)) >> 16);
}
__device__ __forceinline__ float bf2f(u16 u) {
    u32 v = ((u32)u) << 16;
    return __builtin_bit_cast(float, v);
}
__device__ __forceinline__ float bfl(u32 packed) {          // low bf16
    return __builtin_bit_cast(float, packed << 16);
}
__device__ __forceinline__ float bfh(u32 packed) {          // high bf16
    return __builtin_bit_cast(float, packed & 0xFFFF0000u);
}

__device__ __forceinline__ void gll16(const void* g, void* l) {
    __builtin_amdgcn_global_load_lds(
        (const __attribute__((address_space(1))) u32*)g,
        (__attribute__((address_space(3))) u32*)l, 16, 0, 0);
}

#define BAR()  __builtin_amdgcn_s_barrier()
#define WLG0() asm volatile("s_waitcnt lgkmcnt(0)" ::: "memory")
#define WVM0() asm volatile("s_waitcnt vmcnt(0)" ::: "memory")
#define WVM2() asm volatile("s_waitcnt vmcnt(2)" ::: "memory")

// ---------------- CSR build ----------------
__global__ void init_kernel(int* deg, int* fill, int n) {
    int i = blockIdx.x * blockDim.x + threadIdx.x;
    if (i < n) { deg[i] = 1; fill[i] = 0; }
}
__global__ void count_kernel(const int* __restrict__ ei0, int* deg, int e) {
    int i = blockIdx.x * blockDim.x + threadIdx.x;
    if (i < e) atomicAdd(&deg[ei0[i]], 1);
}
__global__ void scan1(const int* __restrict__ deg, int* __restrict__ rowptr,
                      int* __restrict__ bsum, float* __restrict__ dis, int n) {
    __shared__ int sh[SB];
    int tid = threadIdx.x;
    int i = blockIdx.x * SB + tid;
    int v = (i < n) ? deg[i] : 0;
    if (i < n) dis[i] = rsqrtf((float)v);
    sh[tid] = v;
    __syncthreads();
    for (int off = 1; off < SB; off <<= 1) {
        int add = (tid >= off) ? sh[tid - off] : 0;
        __syncthreads();
        sh[tid] += add;
        __syncthreads();
    }
    if (i < n) rowptr[i] = sh[tid] - v;
    if (tid == SB - 1) bsum[blockIdx.x] = sh[tid];
}
__global__ void scan2(const int* __restrict__ bsum, int* __restrict__ bscan, int nb) {
    __shared__ int sh[128];
    int tid = threadIdx.x;
    int v = (tid < nb) ? bsum[tid] : 0;
    sh[tid] = v;
    __syncthreads();
    for (int off = 1; off < 128; off <<= 1) {
        int add = (tid >= off) ? sh[tid - off] : 0;
        __syncthreads();
        sh[tid] += add;
        __syncthreads();
    }
    if (tid < nb) bscan[tid] = sh[tid] - v;
    if (tid == nb - 1) bscan[nb] = sh[tid];
}
__global__ void scan3(int* rowptr, const int* __restrict__ bscan, int n, int nb) {
    int i = blockIdx.x * 256 + threadIdx.x;
    if (i < n) rowptr[i] += bscan[i / SB];
    if (i == n) rowptr[n] = bscan[nb];
}
__global__ void fill_kernel(const int* __restrict__ ei, const float* __restrict__ dis,
                            const int* __restrict__ rowptr, int* fill,
                            int* __restrict__ col, float* __restrict__ wv, int e, int n) {
    int i = blockIdx.x * blockDim.x + threadIdx.x;
    if (i >= e + n) return;
    int r, c;
    if (i < e) { r = ei[i]; c = ei[e + i]; }
    else       { r = i - e; c = r; }
    float w = dis[r] * dis[c];
    int pos = rowptr[r] + atomicAdd(&fill[r], 1);
    col[pos] = c;
    wv[pos]  = w;
}

// ---------------- dtype prep ----------------
__global__ void conv_kernel(const float* __restrict__ x, u16* __restrict__ xb, int total4) {
    int i = blockIdx.x * blockDim.x + threadIdx.x;
    if (i < total4) {
        float4 v = ((const float4*)x)[i];
        ushort4 o;
        o.x = f2bf(v.x); o.y = f2bf(v.y); o.z = f2bf(v.z); o.w = f2bf(v.w);
        ((ushort4*)xb)[i] = o;
    }
}
__global__ void wtrans_kernel(const float* __restrict__ W0, const float* __restrict__ W1,
                              const float* __restrict__ W2, const float* __restrict__ Wc,
                              u16* __restrict__ WkT, u16* __restrict__ WcT) {
    __shared__ u16 tl[64][65];
    int b = blockIdx.x;
    const float* src; u16* dst; int R, C, r0, c0;
    if (b < 48) {
        int k = b >> 4, t = b & 15;
        src = (k == 0) ? W0 : (k == 1) ? W1 : W2;
        dst = WkT + k * 65536;
        R = 256; C = 256; r0 = (t >> 2) * 64; c0 = (t & 3) * 64;
    } else {
        int t = b - 48;
        src = Wc; dst = WcT;
        R = 768; C = 64; r0 = t * 64; c0 = 0;
    }
    int tid = threadIdx.x;
    int rr = tid >> 4, cc = (tid & 15) * 4;
    #pragma unroll
    for (int it = 0; it < 4; ++it) {
        int r = it * 16 + rr;
        float4 v = *(const float4*)(src + (size_t)(r0 + r) * C + c0 + cc);
        tl[cc + 0][r] = f2bf(v.x); tl[cc + 1][r] = f2bf(v.y);
        tl[cc + 2][r] = f2bf(v.z); tl[cc + 3][r] = f2bf(v.w);
    }
    __syncthreads();
    #pragma unroll
    for (int it = 0; it < 4; ++it) {
        int crow = it * 16 + rr;
        ushort4 o;
        o.x = tl[crow][cc + 0]; o.y = tl[crow][cc + 1];
        o.z = tl[crow][cc + 2]; o.w = tl[crow][cc + 3];
        *(ushort4*)(dst + (size_t)(c0 + crow) * R + r0 + cc) = o;
    }
}

// ---------------- SpMM: 2 rows per wave, 32 lanes x 16B each, unroll 8 ----------------
__global__ void spmm_bf16(const int* __restrict__ rowptr, const int* __restrict__ col,
                          const float* __restrict__ wv, const u16* __restrict__ xb,
                          u16* __restrict__ outb, int n) {
    int tid = threadIdx.x;
    int lane = tid & 63;
    int row = blockIdx.x * 8 + ((tid >> 6) << 1) + (lane >> 5);
    if (row >= n) return;
    int l32 = lane & 31;
    int p0 = rowptr[row], p1 = rowptr[row + 1];
    float a[8];
    #pragma unroll
    for (int j = 0; j < 8; ++j) a[j] = 0.f;

    int p = p0;
    for (; p + 8 <= p1; p += 8) {
        int c[8]; float wt[8]; uint4 v[8];
        #pragma unroll
        for (int u = 0; u < 8; ++u) { c[u] = col[p + u]; wt[u] = wv[p + u]; }
        #pragma unroll
        for (int u = 0; u < 8; ++u)
            v[u] = *(const uint4*)(xb + (size_t)c[u] * FD + l32 * 8);
        #pragma unroll
        for (int u = 0; u < 8; ++u) {
            a[0] += wt[u] * bfl(v[u].x); a[1] += wt[u] * bfh(v[u].x);
            a[2] += wt[u] * bfl(v[u].y); a[3] += wt[u] * bfh(v[u].y);
            a[4] += wt[u] * bfl(v[u].z); a[5] += wt[u] * bfh(v[u].z);
            a[6] += wt[u] * bfl(v[u].w); a[7] += wt[u] * bfh(v[u].w);
        }
    }
    for (; p + 2 <= p1; p += 2) {
        int c[2]; float wt[2]; uint4 v[2];
        #pragma unroll
        for (int u = 0; u < 2; ++u) { c[u] = col[p + u]; wt[u] = wv[p + u]; }
        #pragma unroll
        for (int u = 0; u < 2; ++u)
            v[u] = *(const uint4*)(xb + (size_t)c[u] * FD + l32 * 8);
        #pragma unroll
        for (int u = 0; u < 2; ++u) {
            a[0] += wt[u] * bfl(v[u].x); a[1] += wt[u] * bfh(v[u].x);
            a[2] += wt[u] * bfl(v[u].y); a[3] += wt[u] * bfh(v[u].y);
            a[4] += wt[u] * bfl(v[u].z); a[5] += wt[u] * bfh(v[u].z);
            a[6] += wt[u] * bfl(v[u].w); a[7] += wt[u] * bfh(v[u].w);
        }
    }
    for (; p < p1; ++p) {
        int c = col[p];
        float wt = wv[p];
        uint4 v = *(const uint4*)(xb + (size_t)c * FD + l32 * 8);
        a[0] += wt * bfl(v.x); a[1] += wt * bfh(v.x);
        a[2] += wt * bfl(v.y); a[3] += wt * bfh(v.y);
        a[4] += wt * bfl(v.z); a[5] += wt * bfh(v.z);
        a[6] += wt * bfl(v.w); a[7] += wt * bfh(v.w);
    }
    uint4 o;
    o.x = (u32)f2bf(a[0]) | ((u32)f2bf(a[1]) << 16);
    o.y = (u32)f2bf(a[2]) | ((u32)f2bf(a[3]) << 16);
    o.z = (u32)f2bf(a[4]) | ((u32)f2bf(a[5]) << 16);
    o.w = (u32)f2bf(a[6]) | ((u32)f2bf(a[7]) << 16);
    *(uint4*)(outb + (size_t)row * FD + l32 * 8) = o;
}

// ---------------- gemm1: T[seg][r][j] = relu(in_seg @ Wk_seg + bk_seg) ----------------
// m97 structure: 128x128 tile, BK=64, LDS A-tile 16KB + B-tile 16KB (XOR-swizzled
// via pre-swizzled global source), 2 barriers / K-step, 4 K-steps.
__launch_bounds__(256, 3)
__global__ void gemm1(const u16* __restrict__ xb, const u16* __restrict__ agg1b,
                      const u16* __restrict__ agg2b, const u16* __restrict__ WkT,
                      const float* __restrict__ b0, const float* __restrict__ b1,
                      const float* __restrict__ b2, u16* __restrict__ T, int n) {
    __shared__ __align__(16) char lds[32768];   // A [0,16K), B [16K,32K)
    char* lA = lds;
    char* lB = lds + 16384;

    const int tid = threadIdx.x;
    const int w = tid >> 6, l = tid & 63;
    const int l4 = l >> 4, lm = l & 15;
    const int mq = w & 1, nq = w >> 1;          // wave quadrant

    int bid = blockIdx.x;
    const int nt  = bid & 1;          // N-tile (0,1)
    int rest = bid >> 1;
    const int mt  = rest % MT1;
    const int seg = rest / MT1;       // hop 0..2
    const int row0 = mt * 128;
    const int n0   = nt * 128;

    const u16* inb = (seg == 0) ? xb : (seg == 1) ? agg1b : agg2b;
    const u16* WT  = WkT + (size_t)seg * 65536;
    const float* bk = (seg == 0) ? b0 : (seg == 1) ? b1 : b2;

    f32x4 acc[4][4];
    #pragma unroll
    for (int jm = 0; jm < 4; ++jm)
        #pragma unroll
        for (int rn = 0; rn < 4; ++rn) acc[jm][rn] = (f32x4)(0.f);

    for (int kt = 0; kt < 4; ++kt) {
        WLG0();                        // my frag reads of lds done
        BAR();                         // everyone's done -> safe to restage
        #pragma unroll
        for (int c = 0; c < 4; ++c) {  // A-tile: in rows
            int L = w * 1024 + c * 4096 + l * 16;
            int r = L >> 7, s = (L >> 4) & 7;
            int k16 = s ^ (r & 7);
            int gr = row0 + r; if (gr > n - 1) gr = n - 1;
            gll16(inb + (size_t)gr * FD + kt * 64 + k16 * 8, lA + w * 1024 + c * 4096);
        }
        #pragma unroll
        for (int c = 0; c < 4; ++c) {  // B-tile: WkT rows (t-cols)
            int L = w * 1024 + c * 4096 + l * 16;
            int r = L >> 7, s = (L >> 4) & 7;
            int k16 = s ^ (r & 7);
            gll16(WT + (size_t)(n0 + r) * FD + kt * 64 + k16 * 8, lB + w * 1024 + c * 4096);
        }
        WVM0();
        BAR();

        #pragma unroll
        for (int kk2 = 0; kk2 < 2; ++kk2) {
            frag_ab af[4], bf_[4];
            #pragma unroll
            for (int jm = 0; jm < 4; ++jm) {
                int rB = nq * 64 + jm * 16 + lm;
                af[jm] = *(const frag_ab*)(lB + rB * 128 + (((kk2 * 4 + l4) ^ (rB & 7)) << 4));
            }
            #pragma unroll
            for (int rn = 0; rn < 4; ++rn) {
                int rA = mq * 64 + rn * 16 + lm;
                bf_[rn] = *(const frag_ab*)(lA + rA * 128 + (((kk2 * 4 + l4) ^ (rA & 7)) << 4));
            }
            #pragma unroll
            for (int jm = 0; jm < 4; ++jm)
                #pragma unroll
                for (int rn = 0; rn < 4; ++rn)
                    acc[jm][rn] = __builtin_amdgcn_mfma_f32_16x16x32_bf16(af[jm], bf_[rn], acc[jm][rn], 0, 0, 0);
        }
    }

    // epilogue: T[seg][r][j] = relu(acc + bk[j]) as bf16; lane's 4 j contiguous
    u16* Tp = T + (size_t)seg * PS;
    #pragma unroll
    for (int jm = 0; jm < 4; ++jm) {
        int j = n0 + nq * 64 + jm * 16 + l4 * 4;
        float4 bb = *(const float4*)(bk + j);
        #pragma unroll
        for (int rn = 0; rn < 4; ++rn) {
            int r = row0 + mq * 64 + rn * 16 + lm;    // < 50048, in-panel
            f32x4 v = acc[jm][rn];
            ushort4 p;
            p.x = f2bf(fmaxf(v[0] + bb.x, 0.f));
            p.y = f2bf(fmaxf(v[1] + bb.y, 0.f));
            p.z = f2bf(fmaxf(v[2] + bb.z, 0.f));
            p.w = f2bf(fmaxf(v[3] + bb.w, 0.f));
            *(ushort4*)(Tp + (size_t)r * FD + j) = p;
        }
    }
}

// ---------------- gemm2-v3: out[r][c] = sum_q T'[r][q] WcT[c][q] + bc[c] ----------------
// T fragments preloaded into registers (24 x 16B per lane, all in flight at
// once); WcT 64x64 k-slices staged into a 2x8KB LDS ping-pong via
// global_load_lds with counted vmcnt(2). Inner loop = ds_read + MFMA only.
__launch_bounds__(256, 3)
__global__ void gemm2(const u16* __restrict__ T, const u16* __restrict__ WcT,
                      const float* __restrict__ bc, float* __restrict__ out, int n) {
    __shared__ __align__(16) char lds[16384];   // 2 x 8KB WcT slice buffers
    const int tid = threadIdx.x;
    const int w = tid >> 6, l = tid & 63;
    const int l4 = l >> 4, lm = l & 15;
    const int row0 = blockIdx.x * 64;
    const int rr = w * 16 + lm;
    const int r  = row0 + rr;                    // my T row (< 50048, in-panel)

    // preload all 24 T fragments for my row (deep MLP; ~96 VGPRs)
    frag_ab b[24];
    #pragma unroll
    for (int kt = 0; kt < 12; ++kt)
        #pragma unroll
        for (int kk2 = 0; kk2 < 2; ++kk2)
            b[kt * 2 + kk2] = *(const frag_ab*)(T + (size_t)(kt >> 2) * PS +
                                                (size_t)r * FD + (kt & 3) * 64 + kk2 * 32 + l4 * 8);

    // stage WcT slice kt into buf: row c, slot s holds k-chunk (s^(c&7))
    auto stageW = [&](int kt, char* buf) {
        #pragma unroll
        for (int i = 0; i < 2; ++i) {
            int L = tid * 16 + i * 4096;
            int c = L >> 7, s = (L >> 4) & 7;
            gll16(WcT + (size_t)c * 768 + kt * 64 + (s ^ (c & 7)) * 8,
                  buf + w * 1024 + i * 4096);
        }
    };

    f32x4 acc[4];
    #pragma unroll
    for (int am = 0; am < 4; ++am) acc[am] = (f32x4)(0.f);

    stageW(0, lds);
    #pragma unroll
    for (int kt = 0; kt < 12; ++kt) {
        char* cur = lds + (kt & 1) * 8192;
        if (kt < 11) {
            stageW(kt + 1, lds + ((kt + 1) & 1) * 8192);
            WVM2();                    // cur's 2 loads (and all b) landed
        } else {
            WVM0();
        }
        BAR();
        #pragma unroll
        for (int kk2 = 0; kk2 < 2; ++kk2) {
            #pragma unroll
            for (int am = 0; am < 4; ++am) {
                int c = am * 16 + lm;
                frag_ab afr = *(const frag_ab*)(cur + c * 128 + (((kk2 * 4 + l4) ^ (c & 7)) << 4));
                acc[am] = __builtin_amdgcn_mfma_f32_16x16x32_bf16(afr, b[kt * 2 + kk2], acc[am], 0, 0, 0);
            }
        }
        WLG0();                        // my LDS frag reads complete
        BAR();                         // all waves done with cur -> restage ok
    }

    if (r < n) {
        #pragma unroll
        for (int am = 0; am < 4; ++am) {
            float4 bb = *(const float4*)(bc + am * 16 + l4 * 4);
            float4 o;
            o.x = acc[am][0] + bb.x;
            o.y = acc[am][1] + bb.y;
            o.z = acc[am][2] + bb.z;
            o.w = acc[am][3] + bb.w;
            *(float4*)(out + (size_t)r * CO + am * 16 + l4 * 4) = o;
        }
    }
}

extern "C" void kernel_launch(void* const* d_in, const int* in_sizes, int n_in,
                              void* d_out, int out_size, void* d_ws, size_t ws_size,
                              hipStream_t stream) {
    const float* x  = (const float*)d_in[0];
    const int*   ei = (const int*)d_in[1];
    const float* W0 = (const float*)d_in[3];
    const float* b0 = (const float*)d_in[4];
    const float* W1 = (const float*)d_in[5];
    const float* b1 = (const float*)d_in[6];
    const float* W2 = (const float*)d_in[7];
    const float* b2 = (const float*)d_in[8];
    const float* Wc = (const float*)d_in[9];
    const float* bc = (const float*)d_in[10];
    float* out = (float*)d_out;

    const int n  = in_sizes[0] / FD;   // 50000
    const int e  = in_sizes[1] / 2;    // 400000
    const int ep = e + n;
    const int nb = (n + SB - 1) / SB;

    char* ws = (char*)d_ws;
    size_t o = 0;
    auto take = [&](size_t nbytes) -> char* {
        char* p = ws + o;
        o += (nbytes + 255) & ~(size_t)255;
        return p;
    };
    int*   deg    = (int*)  take((size_t)n * 4);
    int*   fill   = (int*)  take((size_t)n * 4);
    float* dis    = (float*)take((size_t)n * 4);
    int*   rowptr = (int*)  take((size_t)(n + 1) * 4);
    int*   bsum   = (int*)  take((size_t)(nb + 1) * 4);
    int*   bscan  = (int*)  take((size_t)(nb + 1) * 4);
    int*   col    = (int*)  take((size_t)ep * 4);
    float* wv     = (float*)take((size_t)ep * 4);
    u16*   xb     = (u16*)  take((size_t)n * FD * 2);
    u16*   agg1b  = (u16*)  take((size_t)n * FD * 2);
    u16*   agg2b  = (u16*)  take((size_t)n * FD * 2);
    u16*   WkT    = (u16*)  take((size_t)3 * FD * FD * 2);
    u16*   WcT    = (u16*)  take((size_t)CO * 3 * FD * 2);
    u16*   T      = (u16*)  take((size_t)3 * PS * 2);
    (void)ws_size; (void)n_in; (void)out_size;

    init_kernel <<<(n + 255) / 256, 256, 0, stream>>>(deg, fill, n);
    count_kernel<<<(e + 255) / 256, 256, 0, stream>>>(ei, deg, e);
    scan1       <<<nb, SB, 0, stream>>>(deg, rowptr, bsum, dis, n);
    scan2       <<<1, 128, 0, stream>>>(bsum, bscan, nb);
    scan3       <<<(n + 256) / 256, 256, 0, stream>>>(rowptr, bscan, n, nb);
    fill_kernel <<<(ep + 255) / 256, 256, 0, stream>>>(ei, dis, rowptr, fill, col, wv, e, n);

    const int total4 = n * FD / 4;
    conv_kernel  <<<(total4 + 255) / 256, 256, 0, stream>>>(x, xb, total4);
    wtrans_kernel<<<60, 256, 0, stream>>>(W0, W1, W2, Wc, WkT, WcT);

    spmm_bf16<<<(n + 7) / 8, 256, 0, stream>>>(rowptr, col, wv, xb, agg1b, n);
    spmm_bf16<<<(n + 7) / 8, 256, 0, stream>>>(rowptr, col, wv, agg1b, agg2b, n);

    gemm1<<<2 * MT1 * 3, 256, 0, stream>>>(xb, agg1b, agg2b, WkT, b0, b1, b2, T, n);
    gemm2<<<(n + 63) / 64, 256, 0, stream>>>(T, WcT, bc, out, n);
}